// Round 10
// baseline (2333.719 us; speedup 1.0000x reference)
//
#include <hip/hip_runtime.h>
#include <hip/hip_bf16.h>
#include <math.h>

#define CDIV(a,b) (((a)+(b)-1)/(b))

// ---------------- problem constants ----------------
#define Bn   8
#define Nn   2000
#define NnP  2048      // Nn padded to K-multiple of 64 (zero-filled)
#define En   512
#define HEN  1024
#define Dn   128
#define HDn  512
#define Pn   8
#define HDE  1024
#define IBn  64
#define TOPK 50

typedef __attribute__((ext_vector_type(8))) short bf16x8;
typedef __attribute__((ext_vector_type(4))) float f32x4;

__device__ __forceinline__ float gelu_exact(float x) {
    return 0.5f * x * (1.0f + erff(x * 0.70710678118654752440f));
}
__device__ __forceinline__ ushort f2b(float f) {          // fp32 -> bf16 RNE
    unsigned u = __float_as_uint(f);
    unsigned r = u + 0x7FFFu + ((u >> 16) & 1u);
    return (ushort)(r >> 16);
}
__device__ __forceinline__ float ld_as_f(const float* p)  { return *p; }
__device__ __forceinline__ float ld_as_f(const ushort* p) { return __uint_as_float(((unsigned)*p) << 16); }

__device__ __forceinline__ void gload16(const ushort* g, ushort* l) {
    __builtin_amdgcn_global_load_lds(
        (const __attribute__((address_space(1))) unsigned int*)(const void*)g,
        (__attribute__((address_space(3))) unsigned int*)(void*)l, 16, 0, 0);
}

// ================= MFMA bf16 GEMM (global_load_lds + XOR swizzle) =================
// UPPER: grid.x = compact linear index over upper-triangle tiles (bx<=by).
#define GBM 128
#define GBN 128
#define GBK 64

template<int ACT, bool ACCUM, bool UPPER, bool OUT_BF16>
__global__ __launch_bounds__(256) void mgemm_k(
    const ushort* __restrict__ A, const ushort* __restrict__ B,
    const float* __restrict__ bias, void* __restrict__ Cv,
    int M, int N, int K,
    long long sA, long long sB, long long sC)
{
    int bx, by;
    if (UPPER) {
        const int t = blockIdx.x;
        by = (int)((sqrtf(8.0f * (float)t + 1.0f) - 1.0f) * 0.5f);
        if (t < by * (by + 1) / 2) --by;
        else if (t >= (by + 1) * (by + 2) / 2) ++by;
        bx = t - by * (by + 1) / 2;           // bx <= by
    } else {
        bx = blockIdx.x; by = blockIdx.y;
    }
    const int bz = blockIdx.z;
    const ushort* Ab = A + (long long)bz * sA;
    const ushort* Bb = B + (long long)bz * sB;
    const int bm0 = bx * GBM;
    const int bn0 = by * GBN;

    __shared__ __align__(16) ushort As[GBM * GBK];
    __shared__ __align__(16) ushort Bs[GBN * GBK];

    const int tid  = threadIdx.x;
    const int lane = tid & 63;
    const int w    = tid >> 6;
    const int wm   = (w >> 1) * 64;
    const int wn   = (w & 1) * 64;
    const int lr   = lane & 15;
    const int hi   = lane >> 4;

    const int srow = lane >> 3;
    const int sch  = (lane & 7) ^ srow;

    f32x4 acc[4][4];
#pragma unroll
    for (int i = 0; i < 4; ++i)
#pragma unroll
        for (int j = 0; j < 4; ++j) acc[i][j] = {0.f, 0.f, 0.f, 0.f};

    const int nK = K / GBK;
    for (int kt = 0; kt < nK; ++kt) {
        const int k0 = kt * GBK;
#pragma unroll
        for (int i = 0; i < 4; ++i) {
            const int r = w * 32 + i * 8 + srow;
            int gm = bm0 + r; if (gm > M - 1) gm = M - 1;
            gload16(Ab + (long long)gm * K + k0 + sch * 8, &As[(w * 32 + i * 8) * GBK]);
            int gn = bn0 + r; if (gn > N - 1) gn = N - 1;
            gload16(Bb + (long long)gn * K + k0 + sch * 8, &Bs[(w * 32 + i * 8) * GBK]);
        }
        __syncthreads();
#pragma unroll
        for (int kk = 0; kk < 2; ++kk) {
            bf16x8 af[4], bfr[4];
#pragma unroll
            for (int i = 0; i < 4; ++i) {
                const int r = wm + i * 16 + lr;
                af[i] = *(const bf16x8*)(&As[r * GBK + (((kk * 4 + hi) ^ (lr & 7)) << 3)]);
            }
#pragma unroll
            for (int j = 0; j < 4; ++j) {
                const int r = wn + j * 16 + lr;
                bfr[j] = *(const bf16x8*)(&Bs[r * GBK + (((kk * 4 + hi) ^ (lr & 7)) << 3)]);
            }
#pragma unroll
            for (int i = 0; i < 4; ++i)
#pragma unroll
                for (int j = 0; j < 4; ++j)
                    acc[i][j] = __builtin_amdgcn_mfma_f32_16x16x32_bf16(af[i], bfr[j], acc[i][j], 0, 0, 0);
        }
        __syncthreads();
    }

    const int crow = hi * 4;
    const int ccol = lr;
#pragma unroll
    for (int i = 0; i < 4; ++i) {
#pragma unroll
        for (int j = 0; j < 4; ++j) {
            const int gn = bn0 + wn + j * 16 + ccol;
            if (gn >= N) continue;
            const float bv = bias ? bias[gn] : 0.0f;
#pragma unroll
            for (int rr = 0; rr < 4; ++rr) {
                const int gm = bm0 + wm + i * 16 + crow + rr;
                if (gm >= M) continue;
                float v = acc[i][j][rr] + bv;
                if (ACT == 1) v = fmaxf(v, 0.0f);
                if (ACT == 2) v = gelu_exact(v);
                const long long idx = (long long)bz * sC + (long long)gm * N + gn;
                if (OUT_BF16) {
                    ((ushort*)Cv)[idx] = f2b(v);
                } else {
                    float* Cf = (float*)Cv;
                    if (ACCUM) Cf[idx] += v; else Cf[idx] = v;
                }
            }
        }
    }
}

// ============ transpose (+convert bf16) with zero-padded output rows ============
template<typename T>
__global__ __launch_bounds__(256) void transpose_pad_k(
    const T* __restrict__ in, ushort* __restrict__ out, int R, int C, int Rpad)
{
    __shared__ float tile[32][33];
    const long long ibase = (long long)blockIdx.z * R * C;
    const long long obase = (long long)blockIdx.z * C * Rpad;
    const int r0 = blockIdx.y * 32, c0 = blockIdx.x * 32;
    const int tx = threadIdx.x & 31, ty = threadIdx.x >> 5;
    for (int i = ty; i < 32; i += 8) {
        const int r = r0 + i, c = c0 + tx;
        float v = 0.0f;
        if (r < R && c < C) v = ld_as_f(in + ibase + (long long)r * C + c);
        tile[i][tx] = v;
    }
    __syncthreads();
    for (int i = ty; i < 32; i += 8) {
        const int c = c0 + i, r = r0 + tx;
        if (c < C && r < Rpad) out[obase + (long long)c * Rpad + r] = f2b(tile[tx][i]);
    }
}

// ============ fused: An[j][i] = (attB[j][i]+delta)*dinv[j]*dinv[i] -> attT[i][jpad] bf16 ============
__global__ __launch_bounds__(256) void normT_k(
    const ushort* __restrict__ attB, const float* __restrict__ dinv, ushort* __restrict__ out)
{
    __shared__ float tile[32][33];
    const int b = blockIdx.z;
    const ushort* A = attB + (long long)b * Nn * Nn;
    ushort* O = out + (long long)b * Nn * NnP;
    const int j0 = blockIdx.y * 32, i0 = blockIdx.x * 32;
    const int tx = threadIdx.x & 31, ty = threadIdx.x >> 5;
    for (int ii = ty; ii < 32; ii += 8) {
        const int j = j0 + ii, i = i0 + tx;
        float v = 0.0f;
        if (j < Nn && i < Nn) {
            v = ld_as_f(A + (long long)j * Nn + i) + ((i == j) ? 1.0f : 0.0f);
            v *= dinv[b * Nn + j] * dinv[b * Nn + i];
        }
        tile[ii][tx] = v;
    }
    __syncthreads();
    for (int ii = ty; ii < 32; ii += 8) {
        const int i = i0 + ii, j = j0 + tx;
        if (i < Nn && j < NnP) O[(long long)i * NnP + j] = f2b(tile[tx][ii]);
    }
}

// ---------------- gate * emb -> bf16 ----------------
__global__ void gate_k(const float* __restrict__ x, const float* __restrict__ gw,
                       const float* __restrict__ gb, const float* __restrict__ emb,
                       ushort* __restrict__ X)
{
    const long long total = (long long)Bn * Nn * En;
    const long long idx = (long long)blockIdx.x * 256 + threadIdx.x;
    if (idx >= total) return;
    const int e = (int)(idx % En);
    const long long bn = idx / En;
    const int n = (int)(bn % Nn);
    const float t = x[bn] * gw[e] + gb[e];
    const float s = 1.0f / (1.0f + expf(-t));
    X[idx] = f2b(s * emb[(long long)n * En + e]);
}

// ---------------- mirror: lower blocks <- transpose(upper) ----------------
__global__ __launch_bounds__(256) void mirror_k(float* __restrict__ att)
{
    const int bi = blockIdx.x, bj = blockIdx.y;
    if (bi <= bj) return;
    float* A = att + (long long)blockIdx.z * Nn * Nn;
    __shared__ float t64[64][65];
    const int ti = threadIdx.x & 63;
    const int tj = threadIdx.x >> 6;
    const int i0 = bi * 64, j0 = bj * 64;
    for (int r = tj; r < 64; r += 4) {
        const int sr = j0 + r, sc = i0 + ti;
        t64[r][ti] = (sr < Nn && sc < Nn) ? A[(long long)sr * Nn + sc] : 0.0f;
    }
    __syncthreads();
    for (int r = tj; r < 64; r += 4) {
        const int dr = i0 + r, dc = j0 + ti;
        if (dr < Nn && dc < Nn) A[(long long)dr * Nn + dc] = t64[ti][r];
    }
}

// -------- top-k + masked softmax -> bf16 att + fused colsum atomics (wave/row) --------
__global__ __launch_bounds__(256) void topk_softmax_k(
    const float* __restrict__ att, ushort* __restrict__ attB, float* __restrict__ colsum)
{
    const int wv = threadIdx.x >> 6;
    const int lane = threadIdx.x & 63;
    const long long row = (long long)blockIdx.x * 4 + wv;
    const float* r = att + row * Nn;

    float v[32];
    const bool v7 = (lane < 52);
#pragma unroll
    for (int i = 0; i < 8; ++i) {
        const int c = lane * 4 + i * 256;
        float4 f = {0.f, 0.f, 0.f, 0.f};
        if (i < 7 || v7) f = *(const float4*)(r + c);
        v[i * 4 + 0] = f.x * 0.125f;
        v[i * 4 + 1] = f.y * 0.125f;
        v[i * 4 + 2] = f.z * 0.125f;
        v[i * 4 + 3] = f.w * 0.125f;
    }

    float m = 0.0f;
#pragma unroll
    for (int i = 0; i < 32; ++i) m = fmaxf(m, v[i]);
#pragma unroll
    for (int s = 1; s < 64; s <<= 1) m = fmaxf(m, __shfl_xor(m, s));

    unsigned lo = 0, hi = __float_as_uint(m);
    while (lo < hi) {
        const unsigned mid = lo + ((hi - lo + 1) >> 1);
        int c = 0;
#pragma unroll
        for (int i = 0; i < 32; ++i) c += (__float_as_uint(v[i]) >= mid) ? 1 : 0;
#pragma unroll
        for (int s = 1; s < 64; s <<= 1) c += __shfl_xor(c, s);
        if (c >= TOPK) lo = mid; else hi = mid - 1;
    }
    const float thr = __uint_as_float(lo);

    float sum = 0.0f;
#pragma unroll
    for (int i = 0; i < 32; ++i) {
        const bool valid = (i < 28) || v7;
        const bool sel = valid && (v[i] >= thr);
        v[i] = sel ? expf(v[i] - m) : 0.0f;
        sum += v[i];
    }
#pragma unroll
    for (int s = 1; s < 64; s <<= 1) sum += __shfl_xor(sum, s);
    const float invZ = 1.0f / sum;

    const int b = (int)(row / Nn);
    float* cs = colsum + b * Nn;
#pragma unroll
    for (int i = 0; i < 8; ++i) {
        const int c = lane * 4 + i * 256;
        if (i < 7 || v7) {
            const float s0 = v[i*4+0] * invZ, s1 = v[i*4+1] * invZ;
            const float s2 = v[i*4+2] * invZ, s3 = v[i*4+3] * invZ;
            ushort4 o = {f2b(s0), f2b(s1), f2b(s2), f2b(s3)};
            *(ushort4*)(attB + row * Nn + c) = o;
            if (s0 > 0.0f) atomicAdd(&cs[c + 0], s0);
            if (s1 > 0.0f) atomicAdd(&cs[c + 1], s1);
            if (s2 > 0.0f) atomicAdd(&cs[c + 2], s2);
            if (s3 > 0.0f) atomicAdd(&cs[c + 3], s3);
        }
    }
}

// ---------------- dinv = rsqrt(1 + colsum) ----------------
__global__ void dinv_k(const float* __restrict__ colsum, float* __restrict__ dinv)
{
    const int i = blockIdx.x * 256 + threadIdx.x;
    if (i < Bn * Nn) dinv[i] = rsqrtf(1.0f + colsum[i]);
}

// ---------------- mean over nodes (2-level, atomic) ----------------
__global__ void mean_k(const float* __restrict__ nout, float* __restrict__ g)
{
    const int b = blockIdx.x;
    const int r0 = blockIdx.y * 200;
    const int col = threadIdx.x & 127, sub = threadIdx.x >> 7;
    float s = 0.0f;
    for (int i = sub * 100; i < sub * 100 + 100; ++i)
        s += nout[((long long)b * Nn + r0 + i) * Dn + col];
    __shared__ float red[256];
    red[threadIdx.x] = s;
    __syncthreads();
    if (sub == 0) atomicAdd(&g[b * Dn + col], (red[col] + red[128 + col]) * (1.0f / Nn));
}

// ---------------- VIB head ----------------
__global__ void vib_k(const float* __restrict__ g, const float* __restrict__ eps,
                      float* __restrict__ mu_out, float* __restrict__ std_out,
                      float* __restrict__ z)
{
    const int t = blockIdx.x * 256 + threadIdx.x;
    if (t >= Bn * IBn) return;
    const int b = t / IBn, d = t % IBn;
    const float mu = g[b * Dn + d];
    const float x = g[b * Dn + IBn + d] - (float)IBn;
    const float sp = (x > 0.0f) ? (x + log1pf(expf(-x))) : log1pf(expf(x));
    mu_out[t] = mu;
    std_out[t] = sp;
    z[t] = mu + eps[t] * sp;
}

// ---------------- decoder layer 1 ----------------
__global__ void dec1_k(const float* __restrict__ z, const float* __restrict__ w1,
                       const float* __restrict__ b1, const float* __restrict__ gamma,
                       const float* __restrict__ beta, float* __restrict__ h)
{
    const int idx = blockIdx.x * 256 + threadIdx.x;
    if (idx >= Bn * HDE) return;
    const int b = idx / HDE, j = idx % HDE;
    float s = b1[j];
    for (int d = 0; d < IBn; ++d) s = fmaf(z[b * IBn + d], w1[d * HDE + j], s);
    s = s * (gamma[j] / sqrtf(1.0f + 1e-5f)) + beta[j];
    h[idx] = fmaxf(s, 0.0f);
}

// ---------------- decoder layer 2 ----------------
__global__ __launch_bounds__(256) void dec2_k(const float* __restrict__ h, const float* __restrict__ w2,
                                              const float* __restrict__ b2, float* __restrict__ out)
{
    __shared__ float hs[Bn * HDE];
    for (int i = threadIdx.x; i < Bn * HDE; i += 256) hs[i] = h[i];
    __syncthreads();
    const int n = blockIdx.x * 256 + threadIdx.x;
    if (n >= Nn) return;
    float acc[Bn];
    const float bb = b2[n];
#pragma unroll
    for (int b = 0; b < Bn; ++b) acc[b] = bb;
    for (int k = 0; k < HDE; ++k) {
        const float wv = w2[(long long)k * Nn + n];
#pragma unroll
        for (int b = 0; b < Bn; ++b) acc[b] = fmaf(hs[b * HDE + k], wv, acc[b]);
    }
#pragma unroll
    for (int b = 0; b < Bn; ++b) out[(long long)b * Nn + n] = fmaxf(acc[b], 0.0f);
}

// ---------------- host ----------------
extern "C" void kernel_launch(void* const* d_in, const int* in_sizes, int n_in,
                              void* d_out, int out_size, void* d_ws, size_t ws_size,
                              hipStream_t stream)
{
    const float* x1     = (const float*)d_in[0];
    const float* x2     = (const float*)d_in[1];
    const float* emb1   = (const float*)d_in[2];
    const float* gate_w = (const float*)d_in[3];
    const float* gate_b = (const float*)d_in[4];
    const float* enc_w1 = (const float*)d_in[5];
    const float* enc_b1 = (const float*)d_in[6];
    const float* enc_w2 = (const float*)d_in[7];
    const float* enc_b2 = (const float*)d_in[8];
    const float* gl_w   = (const float*)d_in[9];
    const float* g_w1   = (const float*)d_in[10];
    const float* g_b1   = (const float*)d_in[11];
    const float* g_w2   = (const float*)d_in[12];
    const float* g_b2   = (const float*)d_in[13];
    const float* g_w3   = (const float*)d_in[14];
    const float* g_b3   = (const float*)d_in[15];
    const float* dec_w1[2] = {(const float*)d_in[16], (const float*)d_in[22]};
    const float* dec_b1[2] = {(const float*)d_in[17], (const float*)d_in[23]};
    const float* dec_g [2] = {(const float*)d_in[18], (const float*)d_in[24]};
    const float* dec_be[2] = {(const float*)d_in[19], (const float*)d_in[25]};
    const float* dec_w2[2] = {(const float*)d_in[20], (const float*)d_in[26]};
    const float* dec_b2[2] = {(const float*)d_in[21], (const float*)d_in[27]};
    const float* epsv  [2] = {(const float*)d_in[28], (const float*)d_in[29]};
    const float* xv    [2] = {x1, x2};

    char* W = (char*)d_ws;
    const int MBN = Bn * Nn;  // 16000

    // ---- workspace layout (bytes) ----
    // R0 [0,128M): att fp32 (syrk/mirror/topk input). Early aliases Xg/henc.
    //   Post-topk (att dead) aliases: attT, ZW, ZWT, bufB, Hout, HbT (127.5 MB total).
    float*  att  = (float*) (W + 0);                     // 128,000,000
    ushort* Xg   = (ushort*)(W + 0);                     // dead before att
    ushort* henc = (ushort*)(W + 16384000);              // dead before att
    ushort* attT = (ushort*)(W + 0);                     // 65,536,000 (8 x 2000 x 2048)
    ushort* ZW   = (ushort*)(W + 65536000);              // 16,384,000
    ushort* ZWT  = (ushort*)(W + 81920000);              // 16,777,216 (8 x 512 x 2048)
    ushort* bufB = (ushort*)(W + 98697216);              // 16,384,000
    float*  Hout = (float*) (W + 115081216);             //  8,192,000
    ushort* HbT  = (ushort*)(W + 123273280);             //  4,194,304 (8 x 128 x 2048)
    // R1 [128M,193.5M): F2 bf16 during syrk; then attB bf16 (topk output, 64 MB)
    ushort* F2   = (ushort*)(W + 128000000);             // 65,536,000 (dead post-syrk)
    ushort* attB = (ushort*)(W + 128000000);             // 64,000,000
    // R2 [193.5M,...): persistent small buffers
    ushort* Hb     = (ushort*)(W + 193536000);           // 4,096,000 (16000x128 bf16)
    ushort* enc_w1T= (ushort*)(W + 197632000);
    ushort* enc_w2T= (ushort*)(W + 198680576);
    ushort* glT    = (ushort*)(W + 198942720);
    ushort* g_w1T  = (ushort*)(W + 199991296);
    ushort* g_w2T  = (ushort*)(W + 200122368);
    ushort* g_w3T  = (ushort*)(W + 200646656);
    float*  dinv   = (float*) (W + 200777728);           // 16000 floats
    float*  gmean  = (float*) (W + 200841728);
    float*  zbuf   = (float*) (W + 200845824);
    float*  hdec   = (float*) (W + 200847872);
    float*  colsum = (float*) (W + 200880640);           // 16000 floats

    const long long sAtt  = (long long)Nn * Nn;
    const long long sF2   = (long long)Nn * NnP;
    const long long sZWT  = (long long)HDn * NnP;
    const long long sBufB = (long long)Nn * HDn;
    const long long sHbT  = (long long)Dn * NnP;
    const long long sP    = (long long)Nn * Dn;
    const long long sZT3  = (long long)Dn * NnP;
    const long long sHout = (long long)Nn * Dn;

    const int NT_UP = (Nn / GBM + 1) * (Nn / GBM + 2) / 2;   // 136 upper tiles

    // ---- weight prep ----
    transpose_pad_k<float><<<dim3(CDIV(HEN,32), CDIV(En,32), 1), 256, 0, stream>>>(enc_w1, enc_w1T, En, HEN, En);
    transpose_pad_k<float><<<dim3(CDIV(Dn,32),  CDIV(HEN,32),1), 256, 0, stream>>>(enc_w2, enc_w2T, HEN, Dn, HEN);
    transpose_pad_k<float><<<dim3(CDIV(HDn,32), CDIV(Dn,32), Pn),256, 0, stream>>>(gl_w,   glT,     Dn,  HDn, Dn);
    transpose_pad_k<float><<<dim3(CDIV(HDn,32), CDIV(Dn,32), 1), 256, 0, stream>>>(g_w1,   g_w1T,   Dn,  HDn, Dn);
    transpose_pad_k<float><<<dim3(CDIV(HDn,32), CDIV(HDn,32),1), 256, 0, stream>>>(g_w2,   g_w2T,   HDn, HDn, HDn);
    transpose_pad_k<float><<<dim3(CDIV(Dn,32),  CDIV(HDn,32),1), 256, 0, stream>>>(g_w3,   g_w3T,   HDn, Dn, HDn);

    for (int g = 0; g < 2; ++g) {
        float* xrec_out = (float*)d_out + g * MBN;
        float* mu_out   = (float*)d_out + 2 * MBN + g * 2 * Bn * IBn;
        float* std_out  = mu_out + Bn * IBn;

        // ---- encoder ----
        gate_k<<<CDIV((long long)MBN * En, 256), 256, 0, stream>>>(xv[g], gate_w, gate_b, emb1, Xg);
        mgemm_k<2,false,false,true><<<dim3(CDIV(MBN,GBM), CDIV(HEN,GBN), 1), 256, 0, stream>>>(
            Xg, enc_w1T, enc_b1, henc, MBN, HEN, En, 0, 0, 0);
        mgemm_k<0,false,false,true><<<dim3(CDIV(MBN,GBM), CDIV(Dn,GBN), 1), 256, 0, stream>>>(
            henc, enc_w2T, enc_b2, Hb, MBN, Dn, HEN, 0, 0, 0);

        // ---- adjacency: att = sum_p relu(H gl_w[p]) relu(H gl_w[p])^T (2 concat-K groups) ----
        for (int g2 = 0; g2 < 2; ++g2) {
            mgemm_k<1,false,false,true><<<dim3(CDIV(MBN,GBM), CDIV(NnP,GBN), 1), 256, 0, stream>>>(
                Hb, glT + (long long)g2 * NnP * Dn, nullptr, F2, MBN, NnP, Dn, 0, 0, 0);
            if (g2 == 0)
                mgemm_k<0,false,true,false><<<dim3(NT_UP, 1, Bn), 256, 0, stream>>>(
                    F2, F2, nullptr, att, Nn, Nn, NnP, sF2, sF2, sAtt);
            else
                mgemm_k<0,true,true,false><<<dim3(NT_UP, 1, Bn), 256, 0, stream>>>(
                    F2, F2, nullptr, att, Nn, Nn, NnP, sF2, sF2, sAtt);
        }
        mirror_k<<<dim3(CDIV(Nn,64), CDIV(Nn,64), Bn), 256, 0, stream>>>(att);

        // ---- top-k+softmax -> bf16 attB + fused colsum; then dinv ----
        hipMemsetAsync(colsum, 0, Bn * Nn * sizeof(float), stream);
        topk_softmax_k<<<CDIV(MBN,4), 256, 0, stream>>>(att, attB, colsum);
        dinv_k<<<CDIV(MBN,256), 256, 0, stream>>>(colsum, dinv);

        // att fp32 dead now: [0,128M) hosts attT/ZW/ZWT/bufB/Hout/HbT
        transpose_pad_k<ushort><<<dim3(CDIV(Dn,32), CDIV(NnP,32), Bn), 256, 0, stream>>>(Hb, HbT, Nn, Dn, NnP);
        normT_k<<<dim3(CDIV(Nn,32), CDIV(NnP,32), Bn), 256, 0, stream>>>(attB, dinv, attT);

        // ---- GCN layer 1 (reassociated: P = An^T * Hb, then bufB = relu(P*W1 + b1)) ----
        mgemm_k<0,false,false,true><<<dim3(CDIV(Nn,GBM), CDIV(Dn,GBN), Bn), 256, 0, stream>>>(
            attT, HbT, nullptr, ZW, Nn, Dn, NnP, sF2, sHbT, sP);
        mgemm_k<1,false,false,true><<<dim3(CDIV(MBN,GBM), CDIV(HDn,GBN), 1), 256, 0, stream>>>(
            ZW, g_w1T, g_b1, bufB, MBN, HDn, Dn, 0, 0, 0);
        // ---- GCN layer 2 ----
        mgemm_k<0,false,false,true><<<dim3(CDIV(MBN,GBM), CDIV(HDn,GBN), 1), 256, 0, stream>>>(
            bufB, g_w2T, nullptr, ZW, MBN, HDn, HDn, 0, 0, 0);
        transpose_pad_k<ushort><<<dim3(CDIV(HDn,32), CDIV(NnP,32), Bn), 256, 0, stream>>>(ZW, ZWT, Nn, HDn, NnP);
        mgemm_k<1,false,false,true><<<dim3(CDIV(Nn,GBM), CDIV(HDn,GBN), Bn), 256, 0, stream>>>(
            attT, ZWT, g_b2, bufB, Nn, HDn, NnP, sF2, sZWT, sBufB);
        // ---- GCN layer 3 ----
        mgemm_k<0,false,false,true><<<dim3(CDIV(MBN,GBM), CDIV(Dn,GBN), 1), 256, 0, stream>>>(
            bufB, g_w3T, nullptr, ZW, MBN, Dn, HDn, 0, 0, 0);
        transpose_pad_k<ushort><<<dim3(CDIV(Dn,32), CDIV(NnP,32), Bn), 256, 0, stream>>>(ZW, ZWT, Nn, Dn, NnP);
        mgemm_k<0,false,false,false><<<dim3(CDIV(Nn,GBM), CDIV(Dn,GBN), Bn), 256, 0, stream>>>(
            attT, ZWT, g_b3, Hout, Nn, Dn, NnP, sF2, sZT3, sHout);

        // ---- readout + VIB + decoder ----
        hipMemsetAsync(gmean, 0, Bn * Dn * sizeof(float), stream);
        mean_k<<<dim3(Bn, 10, 1), 256, 0, stream>>>(Hout, gmean);
        vib_k<<<CDIV(Bn * IBn, 256), 256, 0, stream>>>(gmean, epsv[g], mu_out, std_out, zbuf);
        dec1_k<<<CDIV(Bn * HDE, 256), 256, 0, stream>>>(zbuf, dec_w1[g], dec_b1[g], dec_g[g], dec_be[g], hdec);
        dec2_k<<<CDIV(Nn, 256), 256, 0, stream>>>(hdec, dec_w2[g], dec_b2[g], xrec_out);
    }
}

// Round 11
// 2268.466 us; speedup vs baseline: 1.0288x; 1.0288x over previous
//
#include <hip/hip_runtime.h>
#include <hip/hip_bf16.h>
#include <math.h>

#define CDIV(a,b) (((a)+(b)-1)/(b))

// ---------------- problem constants ----------------
#define Bn   8
#define Nn   2000
#define NnP  2048      // Nn padded to K-multiple of 64 (zero-filled)
#define En   512
#define HEN  1024
#define Dn   128
#define HDn  512
#define Pn   8
#define HDE  1024
#define IBn  64
#define TOPK 50

typedef __attribute__((ext_vector_type(8))) short bf16x8;
typedef __attribute__((ext_vector_type(4))) float f32x4;

__device__ __forceinline__ float gelu_exact(float x) {
    return 0.5f * x * (1.0f + erff(x * 0.70710678118654752440f));
}
__device__ __forceinline__ ushort f2b(float f) {          // fp32 -> bf16 RNE
    unsigned u = __float_as_uint(f);
    unsigned r = u + 0x7FFFu + ((u >> 16) & 1u);
    return (ushort)(r >> 16);
}
__device__ __forceinline__ float ld_as_f(const float* p)  { return *p; }
__device__ __forceinline__ float ld_as_f(const ushort* p) { return __uint_as_float(((unsigned)*p) << 16); }

__device__ __forceinline__ void gload16(const ushort* g, ushort* l) {
    __builtin_amdgcn_global_load_lds(
        (const __attribute__((address_space(1))) unsigned int*)(const void*)g,
        (__attribute__((address_space(3))) unsigned int*)(void*)l, 16, 0, 0);
}

// ================= MFMA bf16 GEMM (global_load_lds + XOR swizzle) =================
// UPPER: grid.x = compact linear index over upper-triangle tiles (bx<=by),
// XCD-swizzled (t' = (t%8)*17 + t/8, bijective for 136 tiles) so each XCD-L2
// sees a contiguous band of the triangle -> smaller panel working set.
// NT: non-temporal fp32 stores (att) -> don't evict F2 operand panels from L2/L3.
#define GBM 128
#define GBN 128
#define GBK 64

template<int ACT, bool ACCUM, bool UPPER, bool OUT_BF16, bool NT = false>
__global__ __launch_bounds__(256) void mgemm_k(
    const ushort* __restrict__ A, const ushort* __restrict__ B,
    const float* __restrict__ bias, void* __restrict__ Cv,
    int M, int N, int K,
    long long sA, long long sB, long long sC)
{
    int bx, by;
    if (UPPER) {
        int t = blockIdx.x;
        if (gridDim.x == 136) t = (t % 8) * 17 + t / 8;   // XCD-locality swizzle
        by = (int)((sqrtf(8.0f * (float)t + 1.0f) - 1.0f) * 0.5f);
        if (t < by * (by + 1) / 2) --by;
        else if (t >= (by + 1) * (by + 2) / 2) ++by;
        bx = t - by * (by + 1) / 2;           // bx <= by
    } else {
        bx = blockIdx.x; by = blockIdx.y;
    }
    const int bz = blockIdx.z;
    const ushort* Ab = A + (long long)bz * sA;
    const ushort* Bb = B + (long long)bz * sB;
    const int bm0 = bx * GBM;
    const int bn0 = by * GBN;

    __shared__ __align__(16) ushort As[GBM * GBK];
    __shared__ __align__(16) ushort Bs[GBN * GBK];

    const int tid  = threadIdx.x;
    const int lane = tid & 63;
    const int w    = tid >> 6;
    const int wm   = (w >> 1) * 64;
    const int wn   = (w & 1) * 64;
    const int lr   = lane & 15;
    const int hi   = lane >> 4;

    const int srow = lane >> 3;
    const int sch  = (lane & 7) ^ srow;

    f32x4 acc[4][4];
#pragma unroll
    for (int i = 0; i < 4; ++i)
#pragma unroll
        for (int j = 0; j < 4; ++j) acc[i][j] = {0.f, 0.f, 0.f, 0.f};

    const int nK = K / GBK;
    for (int kt = 0; kt < nK; ++kt) {
        const int k0 = kt * GBK;
#pragma unroll
        for (int i = 0; i < 4; ++i) {
            const int r = w * 32 + i * 8 + srow;
            int gm = bm0 + r; if (gm > M - 1) gm = M - 1;
            gload16(Ab + (long long)gm * K + k0 + sch * 8, &As[(w * 32 + i * 8) * GBK]);
            int gn = bn0 + r; if (gn > N - 1) gn = N - 1;
            gload16(Bb + (long long)gn * K + k0 + sch * 8, &Bs[(w * 32 + i * 8) * GBK]);
        }
        __syncthreads();
#pragma unroll
        for (int kk = 0; kk < 2; ++kk) {
            bf16x8 af[4], bfr[4];
#pragma unroll
            for (int i = 0; i < 4; ++i) {
                const int r = wm + i * 16 + lr;
                af[i] = *(const bf16x8*)(&As[r * GBK + (((kk * 4 + hi) ^ (lr & 7)) << 3)]);
            }
#pragma unroll
            for (int j = 0; j < 4; ++j) {
                const int r = wn + j * 16 + lr;
                bfr[j] = *(const bf16x8*)(&Bs[r * GBK + (((kk * 4 + hi) ^ (lr & 7)) << 3)]);
            }
#pragma unroll
            for (int i = 0; i < 4; ++i)
#pragma unroll
                for (int j = 0; j < 4; ++j)
                    acc[i][j] = __builtin_amdgcn_mfma_f32_16x16x32_bf16(af[i], bfr[j], acc[i][j], 0, 0, 0);
        }
        __syncthreads();
    }

    const int crow = hi * 4;
    const int ccol = lr;
#pragma unroll
    for (int i = 0; i < 4; ++i) {
#pragma unroll
        for (int j = 0; j < 4; ++j) {
            const int gn = bn0 + wn + j * 16 + ccol;
            if (gn >= N) continue;
            const float bv = bias ? bias[gn] : 0.0f;
#pragma unroll
            for (int rr = 0; rr < 4; ++rr) {
                const int gm = bm0 + wm + i * 16 + crow + rr;
                if (gm >= M) continue;
                float v = acc[i][j][rr] + bv;
                if (ACT == 1) v = fmaxf(v, 0.0f);
                if (ACT == 2) v = gelu_exact(v);
                const long long idx = (long long)bz * sC + (long long)gm * N + gn;
                if (OUT_BF16) {
                    ((ushort*)Cv)[idx] = f2b(v);
                } else {
                    float* Cf = (float*)Cv;
                    if (ACCUM) v += Cf[idx];
                    if (NT) __builtin_nontemporal_store(v, &Cf[idx]);
                    else    Cf[idx] = v;
                }
            }
        }
    }
}

// ============ transpose (+convert bf16) with zero-padded output rows ============
template<typename T>
__global__ __launch_bounds__(256) void transpose_pad_k(
    const T* __restrict__ in, ushort* __restrict__ out, int R, int C, int Rpad)
{
    __shared__ float tile[32][33];
    const long long ibase = (long long)blockIdx.z * R * C;
    const long long obase = (long long)blockIdx.z * C * Rpad;
    const int r0 = blockIdx.y * 32, c0 = blockIdx.x * 32;
    const int tx = threadIdx.x & 31, ty = threadIdx.x >> 5;
    for (int i = ty; i < 32; i += 8) {
        const int r = r0 + i, c = c0 + tx;
        float v = 0.0f;
        if (r < R && c < C) v = ld_as_f(in + ibase + (long long)r * C + c);
        tile[i][tx] = v;
    }
    __syncthreads();
    for (int i = ty; i < 32; i += 8) {
        const int c = c0 + i, r = r0 + tx;
        if (c < C && r < Rpad) out[obase + (long long)c * Rpad + r] = f2b(tile[tx][i]);
    }
}

// ============ fused: An[j][i] = (att[j][i]+delta)*dinv[j]*dinv[i] -> attT[i][jpad] bf16 ============
__global__ __launch_bounds__(256) void normT_k(
    const float* __restrict__ att, const float* __restrict__ dinv, ushort* __restrict__ out)
{
    __shared__ float tile[32][33];
    const int b = blockIdx.z;
    const float* A = att + (long long)b * Nn * Nn;
    ushort* O = out + (long long)b * Nn * NnP;
    const int j0 = blockIdx.y * 32, i0 = blockIdx.x * 32;
    const int tx = threadIdx.x & 31, ty = threadIdx.x >> 5;
    for (int ii = ty; ii < 32; ii += 8) {
        const int j = j0 + ii, i = i0 + tx;
        float v = 0.0f;
        if (j < Nn && i < Nn) {
            v = A[(long long)j * Nn + i] + ((i == j) ? 1.0f : 0.0f);
            v *= dinv[b * Nn + j] * dinv[b * Nn + i];
        }
        tile[ii][tx] = v;
    }
    __syncthreads();
    for (int ii = ty; ii < 32; ii += 8) {
        const int i = i0 + ii, j = j0 + tx;
        if (i < Nn && j < NnP) O[(long long)i * NnP + j] = f2b(tile[tx][ii]);
    }
}

// ---------------- gate * emb -> bf16 ----------------
__global__ void gate_k(const float* __restrict__ x, const float* __restrict__ gw,
                       const float* __restrict__ gb, const float* __restrict__ emb,
                       ushort* __restrict__ X)
{
    const long long total = (long long)Bn * Nn * En;
    const long long idx = (long long)blockIdx.x * 256 + threadIdx.x;
    if (idx >= total) return;
    const int e = (int)(idx % En);
    const long long bn = idx / En;
    const int n = (int)(bn % Nn);
    const float t = x[bn] * gw[e] + gb[e];
    const float s = 1.0f / (1.0f + expf(-t));
    X[idx] = f2b(s * emb[(long long)n * En + e]);
}

// ---------------- mirror: lower blocks <- transpose(upper) ----------------
__global__ __launch_bounds__(256) void mirror_k(float* __restrict__ att)
{
    const int bi = blockIdx.x, bj = blockIdx.y;
    if (bi <= bj) return;
    float* A = att + (long long)blockIdx.z * Nn * Nn;
    __shared__ float t64[64][65];
    const int ti = threadIdx.x & 63;
    const int tj = threadIdx.x >> 6;
    const int i0 = bi * 64, j0 = bj * 64;
    for (int r = tj; r < 64; r += 4) {
        const int sr = j0 + r, sc = i0 + ti;
        t64[r][ti] = (sr < Nn && sc < Nn) ? A[(long long)sr * Nn + sc] : 0.0f;
    }
    __syncthreads();
    for (int r = tj; r < 64; r += 4) {
        const int dr = i0 + r, dc = j0 + ti;
        if (dr < Nn && dc < Nn) A[(long long)dr * Nn + dc] = t64[ti][r];
    }
}

// ---------------- top-k + masked softmax: one wave per row, binary search on bits ----------------
__global__ __launch_bounds__(256) void topk_softmax_k(float* __restrict__ att)
{
    const int wv = threadIdx.x >> 6;
    const int lane = threadIdx.x & 63;
    const long long row = (long long)blockIdx.x * 4 + wv;
    float* r = att + row * Nn;

    float v[32];
    const bool v7 = (lane < 52);
#pragma unroll
    for (int i = 0; i < 8; ++i) {
        const int c = lane * 4 + i * 256;
        float4 f = {0.f, 0.f, 0.f, 0.f};
        if (i < 7 || v7) f = *(const float4*)(r + c);
        v[i * 4 + 0] = f.x * 0.125f;
        v[i * 4 + 1] = f.y * 0.125f;
        v[i * 4 + 2] = f.z * 0.125f;
        v[i * 4 + 3] = f.w * 0.125f;
    }

    float m = 0.0f;
#pragma unroll
    for (int i = 0; i < 32; ++i) m = fmaxf(m, v[i]);
#pragma unroll
    for (int s = 1; s < 64; s <<= 1) m = fmaxf(m, __shfl_xor(m, s));

    unsigned lo = 0, hi = __float_as_uint(m);
    while (lo < hi) {
        const unsigned mid = lo + ((hi - lo + 1) >> 1);
        int c = 0;
#pragma unroll
        for (int i = 0; i < 32; ++i) c += (__float_as_uint(v[i]) >= mid) ? 1 : 0;
#pragma unroll
        for (int s = 1; s < 64; s <<= 1) c += __shfl_xor(c, s);
        if (c >= TOPK) lo = mid; else hi = mid - 1;
    }
    const float thr = __uint_as_float(lo);

    float sum = 0.0f;
#pragma unroll
    for (int i = 0; i < 32; ++i) {
        const bool valid = (i < 28) || v7;
        const bool sel = valid && (v[i] >= thr);
        v[i] = sel ? expf(v[i] - m) : 0.0f;
        sum += v[i];
    }
#pragma unroll
    for (int s = 1; s < 64; s <<= 1) sum += __shfl_xor(sum, s);
    const float invZ = 1.0f / sum;

#pragma unroll
    for (int i = 0; i < 8; ++i) {
        const int c = lane * 4 + i * 256;
        if (i < 7 || v7) {
            float4 o = {v[i*4+0]*invZ, v[i*4+1]*invZ, v[i*4+2]*invZ, v[i*4+3]*invZ};
            *(float4*)(r + c) = o;
        }
    }
}

// ---------------- parallel column sums (j split 16-way, atomic partials) ----------------
__global__ void colsum_k(const float* __restrict__ att, float* __restrict__ colsum)
{
    const int b = blockIdx.z;
    const int i = blockIdx.x * 256 + threadIdx.x;
    if (i >= Nn) return;
    const float* A = att + (long long)b * Nn * Nn;
    const int j0 = blockIdx.y * 125;          // 2000 / 16
    float s = 0.0f;
    for (int j = j0; j < j0 + 125; ++j) s += A[(long long)j * Nn + i];
    atomicAdd(&colsum[b * Nn + i], s);
}

// ---------------- dinv = rsqrt(1 + colsum) ----------------
__global__ void dinv_k(const float* __restrict__ colsum, float* __restrict__ dinv)
{
    const int i = blockIdx.x * 256 + threadIdx.x;
    if (i < Bn * Nn) dinv[i] = rsqrtf(1.0f + colsum[i]);
}

// ---------------- mean over nodes (2-level, atomic) ----------------
__global__ void mean_k(const float* __restrict__ nout, float* __restrict__ g)
{
    const int b = blockIdx.x;
    const int r0 = blockIdx.y * 200;
    const int col = threadIdx.x & 127, sub = threadIdx.x >> 7;
    float s = 0.0f;
    for (int i = sub * 100; i < sub * 100 + 100; ++i)
        s += nout[((long long)b * Nn + r0 + i) * Dn + col];
    __shared__ float red[256];
    red[threadIdx.x] = s;
    __syncthreads();
    if (sub == 0) atomicAdd(&g[b * Dn + col], (red[col] + red[128 + col]) * (1.0f / Nn));
}

// ---------------- VIB head ----------------
__global__ void vib_k(const float* __restrict__ g, const float* __restrict__ eps,
                      float* __restrict__ mu_out, float* __restrict__ std_out,
                      float* __restrict__ z)
{
    const int t = blockIdx.x * 256 + threadIdx.x;
    if (t >= Bn * IBn) return;
    const int b = t / IBn, d = t % IBn;
    const float mu = g[b * Dn + d];
    const float x = g[b * Dn + IBn + d] - (float)IBn;
    const float sp = (x > 0.0f) ? (x + log1pf(expf(-x))) : log1pf(expf(x));
    mu_out[t] = mu;
    std_out[t] = sp;
    z[t] = mu + eps[t] * sp;
}

// ---------------- decoder layer 1 ----------------
__global__ void dec1_k(const float* __restrict__ z, const float* __restrict__ w1,
                       const float* __restrict__ b1, const float* __restrict__ gamma,
                       const float* __restrict__ beta, float* __restrict__ h)
{
    const int idx = blockIdx.x * 256 + threadIdx.x;
    if (idx >= Bn * HDE) return;
    const int b = idx / HDE, j = idx % HDE;
    float s = b1[j];
    for (int d = 0; d < IBn; ++d) s = fmaf(z[b * IBn + d], w1[d * HDE + j], s);
    s = s * (gamma[j] / sqrtf(1.0f + 1e-5f)) + beta[j];
    h[idx] = fmaxf(s, 0.0f);
}

// ---------------- decoder layer 2 ----------------
__global__ __launch_bounds__(256) void dec2_k(const float* __restrict__ h, const float* __restrict__ w2,
                                              const float* __restrict__ b2, float* __restrict__ out)
{
    __shared__ float hs[Bn * HDE];
    for (int i = threadIdx.x; i < Bn * HDE; i += 256) hs[i] = h[i];
    __syncthreads();
    const int n = blockIdx.x * 256 + threadIdx.x;
    if (n >= Nn) return;
    float acc[Bn];
    const float bb = b2[n];
#pragma unroll
    for (int b = 0; b < Bn; ++b) acc[b] = bb;
    for (int k = 0; k < HDE; ++k) {
        const float wv = w2[(long long)k * Nn + n];
#pragma unroll
        for (int b = 0; b < Bn; ++b) acc[b] = fmaf(hs[b * HDE + k], wv, acc[b]);
    }
#pragma unroll
    for (int b = 0; b < Bn; ++b) out[(long long)b * Nn + n] = fmaxf(acc[b], 0.0f);
}

// ---------------- host ----------------
extern "C" void kernel_launch(void* const* d_in, const int* in_sizes, int n_in,
                              void* d_out, int out_size, void* d_ws, size_t ws_size,
                              hipStream_t stream)
{
    const float* x1     = (const float*)d_in[0];
    const float* x2     = (const float*)d_in[1];
    const float* emb1   = (const float*)d_in[2];
    const float* gate_w = (const float*)d_in[3];
    const float* gate_b = (const float*)d_in[4];
    const float* enc_w1 = (const float*)d_in[5];
    const float* enc_b1 = (const float*)d_in[6];
    const float* enc_w2 = (const float*)d_in[7];
    const float* enc_b2 = (const float*)d_in[8];
    const float* gl_w   = (const float*)d_in[9];
    const float* g_w1   = (const float*)d_in[10];
    const float* g_b1   = (const float*)d_in[11];
    const float* g_w2   = (const float*)d_in[12];
    const float* g_b2   = (const float*)d_in[13];
    const float* g_w3   = (const float*)d_in[14];
    const float* g_b3   = (const float*)d_in[15];
    const float* dec_w1[2] = {(const float*)d_in[16], (const float*)d_in[22]};
    const float* dec_b1[2] = {(const float*)d_in[17], (const float*)d_in[23]};
    const float* dec_g [2] = {(const float*)d_in[18], (const float*)d_in[24]};
    const float* dec_be[2] = {(const float*)d_in[19], (const float*)d_in[25]};
    const float* dec_w2[2] = {(const float*)d_in[20], (const float*)d_in[26]};
    const float* dec_b2[2] = {(const float*)d_in[21], (const float*)d_in[27]};
    const float* epsv  [2] = {(const float*)d_in[28], (const float*)d_in[29]};
    const float* xv    [2] = {x1, x2};

    char* W = (char*)d_ws;
    const int MBN = Bn * Nn;  // 16000

    // ---- workspace layout (bytes) ----
    float*  att  = (float*) (W + 0);                     // 128,000,000
    ushort* Xg   = (ushort*)(W + 0);                     // dead before att
    ushort* henc = (ushort*)(W + 16384000);              // dead before att
    ushort* ZW   = (ushort*)(W + 0);                     // att dead post-normT
    ushort* ZWT  = (ushort*)(W + 16384000);              // 16,777,216 (8 x 512 x 2048)
    ushort* bufB = (ushort*)(W + 33161216);              // 16,384,000
    float*  Hout = (float*) (W + 49545216);              //  8,192,000
    ushort* F2   = (ushort*)(W + 128000000);             // 65,536,000
    ushort* attT = (ushort*)(W + 128000000);             // 65,536,000 (F2 dead)
    ushort* Hb     = (ushort*)(W + 193536000);           // 4,096,000
    ushort* enc_w1T= (ushort*)(W + 197632000);
    ushort* enc_w2T= (ushort*)(W + 198680576);
    ushort* glT    = (ushort*)(W + 198942720);
    ushort* g_w1T  = (ushort*)(W + 199991296);
    ushort* g_w2T  = (ushort*)(W + 200122368);
    ushort* g_w3T  = (ushort*)(W + 200646656);
    float*  dinv   = (float*) (W + 200777728);           // 16000 floats
    float*  gmean  = (float*) (W + 200841728);
    float*  zbuf   = (float*) (W + 200845824);
    float*  hdec   = (float*) (W + 200847872);
    float*  colsum = (float*) (W + 200880640);           // 16000 floats

    const long long sAtt  = (long long)Nn * Nn;
    const long long sF2   = (long long)Nn * NnP;
    const long long sZWT  = (long long)HDn * NnP;
    const long long sBufB = (long long)Nn * HDn;
    const long long sZT3  = (long long)Dn * NnP;
    const long long sHout = (long long)Nn * Dn;

    const int NT_UP = (Nn / GBM + 1) * (Nn / GBM + 2) / 2;   // 16*17/2 = 136 upper tiles

    // ---- weight prep ----
    transpose_pad_k<float><<<dim3(CDIV(HEN,32), CDIV(En,32), 1), 256, 0, stream>>>(enc_w1, enc_w1T, En, HEN, En);
    transpose_pad_k<float><<<dim3(CDIV(Dn,32),  CDIV(HEN,32),1), 256, 0, stream>>>(enc_w2, enc_w2T, HEN, Dn, HEN);
    transpose_pad_k<float><<<dim3(CDIV(HDn,32), CDIV(Dn,32), Pn),256, 0, stream>>>(gl_w,   glT,     Dn,  HDn, Dn);
    transpose_pad_k<float><<<dim3(CDIV(HDn,32), CDIV(Dn,32), 1), 256, 0, stream>>>(g_w1,   g_w1T,   Dn,  HDn, Dn);
    transpose_pad_k<float><<<dim3(CDIV(HDn,32), CDIV(HDn,32),1), 256, 0, stream>>>(g_w2,   g_w2T,   HDn, HDn, HDn);
    transpose_pad_k<float><<<dim3(CDIV(Dn,32),  CDIV(HDn,32),1), 256, 0, stream>>>(g_w3,   g_w3T,   HDn, Dn, HDn);

    for (int g = 0; g < 2; ++g) {
        float* xrec_out = (float*)d_out + g * MBN;
        float* mu_out   = (float*)d_out + 2 * MBN + g * 2 * Bn * IBn;
        float* std_out  = mu_out + Bn * IBn;

        // ---- encoder ----
        gate_k<<<CDIV((long long)MBN * En, 256), 256, 0, stream>>>(xv[g], gate_w, gate_b, emb1, Xg);
        mgemm_k<2,false,false,true><<<dim3(CDIV(MBN,GBM), CDIV(HEN,GBN), 1), 256, 0, stream>>>(
            Xg, enc_w1T, enc_b1, henc, MBN, HEN, En, 0, 0, 0);
        mgemm_k<0,false,false,true><<<dim3(CDIV(MBN,GBM), CDIV(Dn,GBN), 1), 256, 0, stream>>>(
            henc, enc_w2T, enc_b2, Hb, MBN, Dn, HEN, 0, 0, 0);

        // ---- adjacency: att = sum_p relu(H gl_w[p]) relu(H gl_w[p])^T (2 concat-K groups) ----
        for (int g2 = 0; g2 < 2; ++g2) {
            mgemm_k<1,false,false,true><<<dim3(CDIV(MBN,GBM), CDIV(NnP,GBN), 1), 256, 0, stream>>>(
                Hb, glT + (long long)g2 * NnP * Dn, nullptr, F2, MBN, NnP, Dn, 0, 0, 0);
            if (g2 == 0)
                mgemm_k<0,false,true,false,true><<<dim3(NT_UP, 1, Bn), 256, 0, stream>>>(
                    F2, F2, nullptr, att, Nn, Nn, NnP, sF2, sF2, sAtt);
            else
                mgemm_k<0,true,true,false,true><<<dim3(NT_UP, 1, Bn), 256, 0, stream>>>(
                    F2, F2, nullptr, att, Nn, Nn, NnP, sF2, sF2, sAtt);
        }
        mirror_k<<<dim3(CDIV(Nn,64), CDIV(Nn,64), Bn), 256, 0, stream>>>(att);
        topk_softmax_k<<<CDIV(MBN,4), 256, 0, stream>>>(att);

        // ---- GCN normalization (parallel colsum; norm+transpose+pad fused) ----
        hipMemsetAsync(colsum, 0, Bn * Nn * sizeof(float), stream);
        colsum_k<<<dim3(CDIV(Nn,256), 16, Bn), 256, 0, stream>>>(att, colsum);
        dinv_k<<<CDIV(MBN,256), 256, 0, stream>>>(colsum, dinv);
        normT_k<<<dim3(CDIV(Nn,32), CDIV(NnP,32), Bn), 256, 0, stream>>>(att, dinv, attT);

        // ---- GCN layer 1 ----
        mgemm_k<0,false,false,true><<<dim3(CDIV(MBN,GBM), CDIV(HDn,GBN), 1), 256, 0, stream>>>(
            Hb, g_w1T, nullptr, ZW, MBN, HDn, Dn, 0, 0, 0);
        transpose_pad_k<ushort><<<dim3(CDIV(HDn,32), CDIV(NnP,32), Bn), 256, 0, stream>>>(ZW, ZWT, Nn, HDn, NnP);
        mgemm_k<1,false,false,true><<<dim3(CDIV(Nn,GBM), CDIV(HDn,GBN), Bn), 256, 0, stream>>>(
            attT, ZWT, g_b1, bufB, Nn, HDn, NnP, sF2, sZWT, sBufB);
        // ---- GCN layer 2 ----
        mgemm_k<0,false,false,true><<<dim3(CDIV(MBN,GBM), CDIV(HDn,GBN), 1), 256, 0, stream>>>(
            bufB, g_w2T, nullptr, ZW, MBN, HDn, HDn, 0, 0, 0);
        transpose_pad_k<ushort><<<dim3(CDIV(HDn,32), CDIV(NnP,32), Bn), 256, 0, stream>>>(ZW, ZWT, Nn, HDn, NnP);
        mgemm_k<1,false,false,true><<<dim3(CDIV(Nn,GBM), CDIV(HDn,GBN), Bn), 256, 0, stream>>>(
            attT, ZWT, g_b2, bufB, Nn, HDn, NnP, sF2, sZWT, sBufB);
        // ---- GCN layer 3 ----
        mgemm_k<0,false,false,true><<<dim3(CDIV(MBN,GBM), CDIV(Dn,GBN), 1), 256, 0, stream>>>(
            bufB, g_w3T, nullptr, ZW, MBN, Dn, HDn, 0, 0, 0);
        transpose_pad_k<ushort><<<dim3(CDIV(Dn,32), CDIV(NnP,32), Bn), 256, 0, stream>>>(ZW, ZWT, Nn, Dn, NnP);
        mgemm_k<0,false,false,false><<<dim3(CDIV(Nn,GBM), CDIV(Dn,GBN), Bn), 256, 0, stream>>>(
            attT, ZWT, g_b3, Hout, Nn, Dn, NnP, sF2, sZT3, sHout);

        // ---- readout + VIB + decoder ----
        hipMemsetAsync(gmean, 0, Bn * Dn * sizeof(float), stream);
        mean_k<<<dim3(Bn, 10, 1), 256, 0, stream>>>(Hout, gmean);
        vib_k<<<CDIV(Bn * IBn, 256), 256, 0, stream>>>(gmean, epsv[g], mu_out, std_out, zbuf);
        dec1_k<<<CDIV(Bn * HDE, 256), 256, 0, stream>>>(zbuf, dec_w1[g], dec_b1[g], dec_g[g], dec_be[g], hdec);
        dec2_k<<<CDIV(Nn, 256), 256, 0, stream>>>(hdec, dec_w2[g], dec_b2[g], xrec_out);
    }
}

// Round 13
// 2217.498 us; speedup vs baseline: 1.0524x; 1.0230x over previous
//
#include <hip/hip_runtime.h>
#include <hip/hip_bf16.h>
#include <math.h>

#define CDIV(a,b) (((a)+(b)-1)/(b))

// ---------------- problem constants ----------------
#define Bn   8
#define Nn   2000
#define NnP  2048      // Nn padded to K-multiple of 64 (zero-filled)
#define En   512
#define HEN  1024
#define Dn   128
#define HDn  512
#define Pn   8
#define HDE  1024
#define IBn  64
#define TOPK 50

typedef __attribute__((ext_vector_type(8))) short bf16x8;
typedef __attribute__((ext_vector_type(4))) float f32x4;

__device__ __forceinline__ float gelu_exact(float x) {
    return 0.5f * x * (1.0f + erff(x * 0.70710678118654752440f));
}
__device__ __forceinline__ ushort f2b(float f) {          // fp32 -> bf16 RNE
    unsigned u = __float_as_uint(f);
    unsigned r = u + 0x7FFFu + ((u >> 16) & 1u);
    return (ushort)(r >> 16);
}
__device__ __forceinline__ float ld_as_f(const float* p)  { return *p; }
__device__ __forceinline__ float ld_as_f(const ushort* p) { return __uint_as_float(((unsigned)*p) << 16); }

__device__ __forceinline__ void gload16(const ushort* g, ushort* l) {
    __builtin_amdgcn_global_load_lds(
        (const __attribute__((address_space(1))) unsigned int*)(const void*)g,
        (__attribute__((address_space(3))) unsigned int*)(void*)l, 16, 0, 0);
}

// ================= MFMA bf16 GEMM (global_load_lds + XOR swizzle) =================
// UPPER: grid.x = compact linear index over upper-triangle tiles (bx<=by),
// XCD-swizzled (t' = (t%8)*17 + t/8, bijective for 136 tiles) so each XCD-L2
// sees a contiguous band of the triangle -> smaller panel working set.
#define GBM 128
#define GBN 128
#define GBK 64

template<int ACT, bool ACCUM, bool UPPER, bool OUT_BF16>
__global__ __launch_bounds__(256) void mgemm_k(
    const ushort* __restrict__ A, const ushort* __restrict__ B,
    const float* __restrict__ bias, void* __restrict__ Cv,
    int M, int N, int K,
    long long sA, long long sB, long long sC)
{
    int bx, by;
    if (UPPER) {
        int t = blockIdx.x;
        if (gridDim.x == 136) t = (t % 8) * 17 + t / 8;   // XCD-locality swizzle
        by = (int)((sqrtf(8.0f * (float)t + 1.0f) - 1.0f) * 0.5f);
        if (t < by * (by + 1) / 2) --by;
        else if (t >= (by + 1) * (by + 2) / 2) ++by;
        bx = t - by * (by + 1) / 2;           // bx <= by
    } else {
        bx = blockIdx.x; by = blockIdx.y;
    }
    const int bz = blockIdx.z;
    const ushort* Ab = A + (long long)bz * sA;
    const ushort* Bb = B + (long long)bz * sB;
    const int bm0 = bx * GBM;
    const int bn0 = by * GBN;

    __shared__ __align__(16) ushort As[GBM * GBK];
    __shared__ __align__(16) ushort Bs[GBN * GBK];

    const int tid  = threadIdx.x;
    const int lane = tid & 63;
    const int w    = tid >> 6;
    const int wm   = (w >> 1) * 64;
    const int wn   = (w & 1) * 64;
    const int lr   = lane & 15;
    const int hi   = lane >> 4;

    const int srow = lane >> 3;
    const int sch  = (lane & 7) ^ srow;

    f32x4 acc[4][4];
#pragma unroll
    for (int i = 0; i < 4; ++i)
#pragma unroll
        for (int j = 0; j < 4; ++j) acc[i][j] = {0.f, 0.f, 0.f, 0.f};

    const int nK = K / GBK;
    for (int kt = 0; kt < nK; ++kt) {
        const int k0 = kt * GBK;
#pragma unroll
        for (int i = 0; i < 4; ++i) {
            const int r = w * 32 + i * 8 + srow;
            int gm = bm0 + r; if (gm > M - 1) gm = M - 1;
            gload16(Ab + (long long)gm * K + k0 + sch * 8, &As[(w * 32 + i * 8) * GBK]);
            int gn = bn0 + r; if (gn > N - 1) gn = N - 1;
            gload16(Bb + (long long)gn * K + k0 + sch * 8, &Bs[(w * 32 + i * 8) * GBK]);
        }
        __syncthreads();
#pragma unroll
        for (int kk = 0; kk < 2; ++kk) {
            bf16x8 af[4], bfr[4];
#pragma unroll
            for (int i = 0; i < 4; ++i) {
                const int r = wm + i * 16 + lr;
                af[i] = *(const bf16x8*)(&As[r * GBK + (((kk * 4 + hi) ^ (lr & 7)) << 3)]);
            }
#pragma unroll
            for (int j = 0; j < 4; ++j) {
                const int r = wn + j * 16 + lr;
                bfr[j] = *(const bf16x8*)(&Bs[r * GBK + (((kk * 4 + hi) ^ (lr & 7)) << 3)]);
            }
#pragma unroll
            for (int i = 0; i < 4; ++i)
#pragma unroll
                for (int j = 0; j < 4; ++j)
                    acc[i][j] = __builtin_amdgcn_mfma_f32_16x16x32_bf16(af[i], bfr[j], acc[i][j], 0, 0, 0);
        }
        __syncthreads();
    }

    const int crow = hi * 4;
    const int ccol = lr;
#pragma unroll
    for (int i = 0; i < 4; ++i) {
#pragma unroll
        for (int j = 0; j < 4; ++j) {
            const int gn = bn0 + wn + j * 16 + ccol;
            if (gn >= N) continue;
            const float bv = bias ? bias[gn] : 0.0f;
#pragma unroll
            for (int rr = 0; rr < 4; ++rr) {
                const int gm = bm0 + wm + i * 16 + crow + rr;
                if (gm >= M) continue;
                float v = acc[i][j][rr] + bv;
                if (ACT == 1) v = fmaxf(v, 0.0f);
                if (ACT == 2) v = gelu_exact(v);
                const long long idx = (long long)bz * sC + (long long)gm * N + gn;
                if (OUT_BF16) {
                    ((ushort*)Cv)[idx] = f2b(v);
                } else {
                    float* Cf = (float*)Cv;
                    if (ACCUM) Cf[idx] += v; else Cf[idx] = v;
                }
            }
        }
    }
}

// ============ transpose (+convert bf16) with zero-padded output rows ============
template<typename T>
__global__ __launch_bounds__(256) void transpose_pad_k(
    const T* __restrict__ in, ushort* __restrict__ out, int R, int C, int Rpad)
{
    __shared__ float tile[32][33];
    const long long ibase = (long long)blockIdx.z * R * C;
    const long long obase = (long long)blockIdx.z * C * Rpad;
    const int r0 = blockIdx.y * 32, c0 = blockIdx.x * 32;
    const int tx = threadIdx.x & 31, ty = threadIdx.x >> 5;
    for (int i = ty; i < 32; i += 8) {
        const int r = r0 + i, c = c0 + tx;
        float v = 0.0f;
        if (r < R && c < C) v = ld_as_f(in + ibase + (long long)r * C + c);
        tile[i][tx] = v;
    }
    __syncthreads();
    for (int i = ty; i < 32; i += 8) {
        const int c = c0 + i, r = r0 + tx;
        if (c < C && r < Rpad) out[obase + (long long)c * Rpad + r] = f2b(tile[tx][i]);
    }
}

// ============ fused: An[j][i] = (att[j][i]+delta)*dinv[j]*dinv[i] -> attT[i][jpad] bf16 ============
__global__ __launch_bounds__(256) void normT_k(
    const float* __restrict__ att, const float* __restrict__ dinv, ushort* __restrict__ out)
{
    __shared__ float tile[32][33];
    const int b = blockIdx.z;
    const float* A = att + (long long)b * Nn * Nn;
    ushort* O = out + (long long)b * Nn * NnP;
    const int j0 = blockIdx.y * 32, i0 = blockIdx.x * 32;
    const int tx = threadIdx.x & 31, ty = threadIdx.x >> 5;
    for (int ii = ty; ii < 32; ii += 8) {
        const int j = j0 + ii, i = i0 + tx;
        float v = 0.0f;
        if (j < Nn && i < Nn) {
            v = A[(long long)j * Nn + i] + ((i == j) ? 1.0f : 0.0f);
            v *= dinv[b * Nn + j] * dinv[b * Nn + i];
        }
        tile[ii][tx] = v;
    }
    __syncthreads();
    for (int ii = ty; ii < 32; ii += 8) {
        const int i = i0 + ii, j = j0 + tx;
        if (i < Nn && j < NnP) O[(long long)i * NnP + j] = f2b(tile[tx][ii]);
    }
}

// ---------------- gate * emb -> bf16 ----------------
__global__ void gate_k(const float* __restrict__ x, const float* __restrict__ gw,
                       const float* __restrict__ gb, const float* __restrict__ emb,
                       ushort* __restrict__ X)
{
    const long long total = (long long)Bn * Nn * En;
    const long long idx = (long long)blockIdx.x * 256 + threadIdx.x;
    if (idx >= total) return;
    const int e = (int)(idx % En);
    const long long bn = idx / En;
    const int n = (int)(bn % Nn);
    const float t = x[bn] * gw[e] + gb[e];
    const float s = 1.0f / (1.0f + expf(-t));
    X[idx] = f2b(s * emb[(long long)n * En + e]);
}

// ---------------- mirror: lower blocks <- transpose(upper) ----------------
__global__ __launch_bounds__(256) void mirror_k(float* __restrict__ att)
{
    const int bi = blockIdx.x, bj = blockIdx.y;
    if (bi <= bj) return;
    float* A = att + (long long)blockIdx.z * Nn * Nn;
    __shared__ float t64[64][65];
    const int ti = threadIdx.x & 63;
    const int tj = threadIdx.x >> 6;
    const int i0 = bi * 64, j0 = bj * 64;
    for (int r = tj; r < 64; r += 4) {
        const int sr = j0 + r, sc = i0 + ti;
        t64[r][ti] = (sr < Nn && sc < Nn) ? A[(long long)sr * Nn + sc] : 0.0f;
    }
    __syncthreads();
    for (int r = tj; r < 64; r += 4) {
        const int dr = i0 + r, dc = j0 + ti;
        if (dr < Nn && dc < Nn) A[(long long)dr * Nn + dc] = t64[ti][r];
    }
}

// ---------------- top-k + masked softmax: one wave per row, binary search on bits ----------------
__global__ __launch_bounds__(256) void topk_softmax_k(float* __restrict__ att)
{
    const int wv = threadIdx.x >> 6;
    const int lane = threadIdx.x & 63;
    const long long row = (long long)blockIdx.x * 4 + wv;
    float* r = att + row * Nn;

    float v[32];
    const bool v7 = (lane < 52);
#pragma unroll
    for (int i = 0; i < 8; ++i) {
        const int c = lane * 4 + i * 256;
        float4 f = {0.f, 0.f, 0.f, 0.f};
        if (i < 7 || v7) f = *(const float4*)(r + c);
        v[i * 4 + 0] = f.x * 0.125f;
        v[i * 4 + 1] = f.y * 0.125f;
        v[i * 4 + 2] = f.z * 0.125f;
        v[i * 4 + 3] = f.w * 0.125f;
    }

    float m = 0.0f;
#pragma unroll
    for (int i = 0; i < 32; ++i) m = fmaxf(m, v[i]);
#pragma unroll
    for (int s = 1; s < 64; s <<= 1) m = fmaxf(m, __shfl_xor(m, s));

    unsigned lo = 0, hi = __float_as_uint(m);
    while (lo < hi) {
        const unsigned mid = lo + ((hi - lo + 1) >> 1);
        int c = 0;
#pragma unroll
        for (int i = 0; i < 32; ++i) c += (__float_as_uint(v[i]) >= mid) ? 1 : 0;
#pragma unroll
        for (int s = 1; s < 64; s <<= 1) c += __shfl_xor(c, s);
        if (c >= TOPK) lo = mid; else hi = mid - 1;
    }
    const float thr = __uint_as_float(lo);

    float sum = 0.0f;
#pragma unroll
    for (int i = 0; i < 32; ++i) {
        const bool valid = (i < 28) || v7;
        const bool sel = valid && (v[i] >= thr);
        v[i] = sel ? expf(v[i] - m) : 0.0f;
        sum += v[i];
    }
#pragma unroll
    for (int s = 1; s < 64; s <<= 1) sum += __shfl_xor(sum, s);
    const float invZ = 1.0f / sum;

#pragma unroll
    for (int i = 0; i < 8; ++i) {
        const int c = lane * 4 + i * 256;
        if (i < 7 || v7) {
            float4 o = {v[i*4+0]*invZ, v[i*4+1]*invZ, v[i*4+2]*invZ, v[i*4+3]*invZ};
            *(float4*)(r + c) = o;
        }
    }
}

// ---------------- parallel column sums (j split 16-way, atomic partials) ----------------
__global__ void colsum_k(const float* __restrict__ att, float* __restrict__ colsum)
{
    const int b = blockIdx.z;
    const int i = blockIdx.x * 256 + threadIdx.x;
    if (i >= Nn) return;
    const float* A = att + (long long)b * Nn * Nn;
    const int j0 = blockIdx.y * 125;          // 2000 / 16
    float s = 0.0f;
    for (int j = j0; j < j0 + 125; ++j) s += A[(long long)j * Nn + i];
    atomicAdd(&colsum[b * Nn + i], s);
}

// ---------------- dinv = rsqrt(1 + colsum) ----------------
__global__ void dinv_k(const float* __restrict__ colsum, float* __restrict__ dinv)
{
    const int i = blockIdx.x * 256 + threadIdx.x;
    if (i < Bn * Nn) dinv[i] = rsqrtf(1.0f + colsum[i]);
}

// ---------------- mean over nodes (2-level, atomic) ----------------
__global__ void mean_k(const float* __restrict__ nout, float* __restrict__ g)
{
    const int b = blockIdx.x;
    const int r0 = blockIdx.y * 200;
    const int col = threadIdx.x & 127, sub = threadIdx.x >> 7;
    float s = 0.0f;
    for (int i = sub * 100; i < sub * 100 + 100; ++i)
        s += nout[((long long)b * Nn + r0 + i) * Dn + col];
    __shared__ float red[256];
    red[threadIdx.x] = s;
    __syncthreads();
    if (sub == 0) atomicAdd(&g[b * Dn + col], (red[col] + red[128 + col]) * (1.0f / Nn));
}

// ---------------- VIB head ----------------
__global__ void vib_k(const float* __restrict__ g, const float* __restrict__ eps,
                      float* __restrict__ mu_out, float* __restrict__ std_out,
                      float* __restrict__ z)
{
    const int t = blockIdx.x * 256 + threadIdx.x;
    if (t >= Bn * IBn) return;
    const int b = t / IBn, d = t % IBn;
    const float mu = g[b * Dn + d];
    const float x = g[b * Dn + IBn + d] - (float)IBn;
    const float sp = (x > 0.0f) ? (x + log1pf(expf(-x))) : log1pf(expf(x));
    mu_out[t] = mu;
    std_out[t] = sp;
    z[t] = mu + eps[t] * sp;
}

// ---------------- decoder layer 1 ----------------
__global__ void dec1_k(const float* __restrict__ z, const float* __restrict__ w1,
                       const float* __restrict__ b1, const float* __restrict__ gamma,
                       const float* __restrict__ beta, float* __restrict__ h)
{
    const int idx = blockIdx.x * 256 + threadIdx.x;
    if (idx >= Bn * HDE) return;
    const int b = idx / HDE, j = idx % HDE;
    float s = b1[j];
    for (int d = 0; d < IBn; ++d) s = fmaf(z[b * IBn + d], w1[d * HDE + j], s);
    s = s * (gamma[j] / sqrtf(1.0f + 1e-5f)) + beta[j];
    h[idx] = fmaxf(s, 0.0f);
}

// ---------------- decoder layer 2 ----------------
__global__ __launch_bounds__(256) void dec2_k(const float* __restrict__ h, const float* __restrict__ w2,
                                              const float* __restrict__ b2, float* __restrict__ out)
{
    __shared__ float hs[Bn * HDE];
    for (int i = threadIdx.x; i < Bn * HDE; i += 256) hs[i] = h[i];
    __syncthreads();
    const int n = blockIdx.x * 256 + threadIdx.x;
    if (n >= Nn) return;
    float acc[Bn];
    const float bb = b2[n];
#pragma unroll
    for (int b = 0; b < Bn; ++b) acc[b] = bb;
    for (int k = 0; k < HDE; ++k) {
        const float wv = w2[(long long)k * Nn + n];
#pragma unroll
        for (int b = 0; b < Bn; ++b) acc[b] = fmaf(hs[b * HDE + k], wv, acc[b]);
    }
#pragma unroll
    for (int b = 0; b < Bn; ++b) out[(long long)b * Nn + n] = fmaxf(acc[b], 0.0f);
}

// ---------------- host ----------------
extern "C" void kernel_launch(void* const* d_in, const int* in_sizes, int n_in,
                              void* d_out, int out_size, void* d_ws, size_t ws_size,
                              hipStream_t stream)
{
    const float* x1     = (const float*)d_in[0];
    const float* x2     = (const float*)d_in[1];
    const float* emb1   = (const float*)d_in[2];
    const float* gate_w = (const float*)d_in[3];
    const float* gate_b = (const float*)d_in[4];
    const float* enc_w1 = (const float*)d_in[5];
    const float* enc_b1 = (const float*)d_in[6];
    const float* enc_w2 = (const float*)d_in[7];
    const float* enc_b2 = (const float*)d_in[8];
    const float* gl_w   = (const float*)d_in[9];
    const float* g_w1   = (const float*)d_in[10];
    const float* g_b1   = (const float*)d_in[11];
    const float* g_w2   = (const float*)d_in[12];
    const float* g_b2   = (const float*)d_in[13];
    const float* g_w3   = (const float*)d_in[14];
    const float* g_b3   = (const float*)d_in[15];
    const float* dec_w1[2] = {(const float*)d_in[16], (const float*)d_in[22]};
    const float* dec_b1[2] = {(const float*)d_in[17], (const float*)d_in[23]};
    const float* dec_g [2] = {(const float*)d_in[18], (const float*)d_in[24]};
    const float* dec_be[2] = {(const float*)d_in[19], (const float*)d_in[25]};
    const float* dec_w2[2] = {(const float*)d_in[20], (const float*)d_in[26]};
    const float* dec_b2[2] = {(const float*)d_in[21], (const float*)d_in[27]};
    const float* epsv  [2] = {(const float*)d_in[28], (const float*)d_in[29]};
    const float* xv    [2] = {x1, x2};

    char* W = (char*)d_ws;
    const int MBN = Bn * Nn;  // 16000

    // ---- workspace layout (bytes) ----
    float*  att  = (float*) (W + 0);                     // 128,000,000
    ushort* Xg   = (ushort*)(W + 0);                     // dead before att
    ushort* henc = (ushort*)(W + 16384000);              // dead before att
    ushort* ZW   = (ushort*)(W + 0);                     // att dead post-normT
    ushort* ZWT  = (ushort*)(W + 16384000);              // 16,777,216 (8 x 512 x 2048)
    ushort* bufB = (ushort*)(W + 33161216);              // 16,384,000
    float*  Hout = (float*) (W + 49545216);              //  8,192,000
    ushort* F2   = (ushort*)(W + 128000000);             // 65,536,000
    ushort* attT = (ushort*)(W + 128000000);             // 65,536,000 (F2 dead)
    ushort* Hb     = (ushort*)(W + 193536000);           // 4,096,000
    ushort* enc_w1T= (ushort*)(W + 197632000);
    ushort* enc_w2T= (ushort*)(W + 198680576);
    ushort* glT    = (ushort*)(W + 198942720);
    ushort* g_w1T  = (ushort*)(W + 199991296);
    ushort* g_w2T  = (ushort*)(W + 200122368);
    ushort* g_w3T  = (ushort*)(W + 200646656);
    float*  dinv   = (float*) (W + 200777728);           // 16000 floats
    float*  gmean  = (float*) (W + 200841728);
    float*  zbuf   = (float*) (W + 200845824);
    float*  hdec   = (float*) (W + 200847872);
    float*  colsum = (float*) (W + 200880640);           // 16000 floats

    const long long sAtt  = (long long)Nn * Nn;
    const long long sF2   = (long long)Nn * NnP;
    const long long sZWT  = (long long)HDn * NnP;
    const long long sBufB = (long long)Nn * HDn;
    const long long sZT3  = (long long)Dn * NnP;
    const long long sHout = (long long)Nn * Dn;

    const int NT_UP = (Nn / GBM + 1) * (Nn / GBM + 2) / 2;   // 16*17/2 = 136 upper tiles

    // ---- weight prep ----
    transpose_pad_k<float><<<dim3(CDIV(HEN,32), CDIV(En,32), 1), 256, 0, stream>>>(enc_w1, enc_w1T, En, HEN, En);
    transpose_pad_k<float><<<dim3(CDIV(Dn,32),  CDIV(HEN,32),1), 256, 0, stream>>>(enc_w2, enc_w2T, HEN, Dn, HEN);
    transpose_pad_k<float><<<dim3(CDIV(HDn,32), CDIV(Dn,32), Pn),256, 0, stream>>>(gl_w,   glT,     Dn,  HDn, Dn);
    transpose_pad_k<float><<<dim3(CDIV(HDn,32), CDIV(Dn,32), 1), 256, 0, stream>>>(g_w1,   g_w1T,   Dn,  HDn, Dn);
    transpose_pad_k<float><<<dim3(CDIV(HDn,32), CDIV(HDn,32),1), 256, 0, stream>>>(g_w2,   g_w2T,   HDn, HDn, HDn);
    transpose_pad_k<float><<<dim3(CDIV(Dn,32),  CDIV(HDn,32),1), 256, 0, stream>>>(g_w3,   g_w3T,   HDn, Dn, HDn);

    for (int g = 0; g < 2; ++g) {
        float* xrec_out = (float*)d_out + g * MBN;
        float* mu_out   = (float*)d_out + 2 * MBN + g * 2 * Bn * IBn;
        float* std_out  = mu_out + Bn * IBn;

        // ---- encoder ----
        gate_k<<<CDIV((long long)MBN * En, 256), 256, 0, stream>>>(xv[g], gate_w, gate_b, emb1, Xg);
        mgemm_k<2,false,false,true><<<dim3(CDIV(MBN,GBM), CDIV(HEN,GBN), 1), 256, 0, stream>>>(
            Xg, enc_w1T, enc_b1, henc, MBN, HEN, En, 0, 0, 0);
        mgemm_k<0,false,false,true><<<dim3(CDIV(MBN,GBM), CDIV(Dn,GBN), 1), 256, 0, stream>>>(
            henc, enc_w2T, enc_b2, Hb, MBN, Dn, HEN, 0, 0, 0);

        // ---- adjacency: att = sum_p relu(H gl_w[p]) relu(H gl_w[p])^T (2 concat-K groups) ----
        for (int g2 = 0; g2 < 2; ++g2) {
            mgemm_k<1,false,false,true><<<dim3(CDIV(MBN,GBM), CDIV(NnP,GBN), 1), 256, 0, stream>>>(
                Hb, glT + (long long)g2 * NnP * Dn, nullptr, F2, MBN, NnP, Dn, 0, 0, 0);
            if (g2 == 0)
                mgemm_k<0,false,true,false><<<dim3(NT_UP, 1, Bn), 256, 0, stream>>>(
                    F2, F2, nullptr, att, Nn, Nn, NnP, sF2, sF2, sAtt);
            else
                mgemm_k<0,true,true,false><<<dim3(NT_UP, 1, Bn), 256, 0, stream>>>(
                    F2, F2, nullptr, att, Nn, Nn, NnP, sF2, sF2, sAtt);
        }
        mirror_k<<<dim3(CDIV(Nn,64), CDIV(Nn,64), Bn), 256, 0, stream>>>(att);
        topk_softmax_k<<<CDIV(MBN,4), 256, 0, stream>>>(att);

        // ---- GCN normalization (parallel colsum; norm+transpose+pad fused) ----
        hipMemsetAsync(colsum, 0, Bn * Nn * sizeof(float), stream);
        colsum_k<<<dim3(CDIV(Nn,256), 16, Bn), 256, 0, stream>>>(att, colsum);
        dinv_k<<<CDIV(MBN,256), 256, 0, stream>>>(colsum, dinv);
        normT_k<<<dim3(CDIV(Nn,32), CDIV(NnP,32), Bn), 256, 0, stream>>>(att, dinv, attT);

        // ---- GCN layer 1 ----
        mgemm_k<0,false,false,true><<<dim3(CDIV(MBN,GBM), CDIV(HDn,GBN), 1), 256, 0, stream>>>(
            Hb, g_w1T, nullptr, ZW, MBN, HDn, Dn, 0, 0, 0);
        transpose_pad_k<ushort><<<dim3(CDIV(HDn,32), CDIV(NnP,32), Bn), 256, 0, stream>>>(ZW, ZWT, Nn, HDn, NnP);
        mgemm_k<1,false,false,true><<<dim3(CDIV(Nn,GBM), CDIV(HDn,GBN), Bn), 256, 0, stream>>>(
            attT, ZWT, g_b1, bufB, Nn, HDn, NnP, sF2, sZWT, sBufB);
        // ---- GCN layer 2 ----
        mgemm_k<0,false,false,true><<<dim3(CDIV(MBN,GBM), CDIV(HDn,GBN), 1), 256, 0, stream>>>(
            bufB, g_w2T, nullptr, ZW, MBN, HDn, HDn, 0, 0, 0);
        transpose_pad_k<ushort><<<dim3(CDIV(HDn,32), CDIV(NnP,32), Bn), 256, 0, stream>>>(ZW, ZWT, Nn, HDn, NnP);
        mgemm_k<1,false,false,true><<<dim3(CDIV(Nn,GBM), CDIV(HDn,GBN), Bn), 256, 0, stream>>>(
            attT, ZWT, g_b2, bufB, Nn, HDn, NnP, sF2, sZWT, sBufB);
        // ---- GCN layer 3 ----
        mgemm_k<0,false,false,true><<<dim3(CDIV(MBN,GBM), CDIV(Dn,GBN), 1), 256, 0, stream>>>(
            bufB, g_w3T, nullptr, ZW, MBN, Dn, HDn, 0, 0, 0);
        transpose_pad_k<ushort><<<dim3(CDIV(Dn,32), CDIV(NnP,32), Bn), 256, 0, stream>>>(ZW, ZWT, Nn, Dn, NnP);
        mgemm_k<0,false,false,false><<<dim3(CDIV(Nn,GBM), CDIV(Dn,GBN), Bn), 256, 0, stream>>>(
            attT, ZWT, g_b3, Hout, Nn, Dn, NnP, sF2, sZT3, sHout);

        // ---- readout + VIB + decoder ----
        hipMemsetAsync(gmean, 0, Bn * Dn * sizeof(float), stream);
        mean_k<<<dim3(Bn, 10, 1), 256, 0, stream>>>(Hout, gmean);
        vib_k<<<CDIV(Bn * IBn, 256), 256, 0, stream>>>(gmean, epsv[g], mu_out, std_out, zbuf);
        dec1_k<<<CDIV(Bn * HDE, 256), 256, 0, stream>>>(zbuf, dec_w1[g], dec_b1[g], dec_g[g], dec_be[g], hdec);
        dec2_k<<<CDIV(Nn, 256), 256, 0, stream>>>(hdec, dec_w2[g], dec_b2[g], xrec_out);
    }
}